// Round 1
// baseline (603.665 us; speedup 1.0000x reference)
//
#include <hip/hip_runtime.h>

#define N_TOK 8192
#define DIM   2048
#define HID   2048
#define NE    8

typedef unsigned short u16;
typedef __attribute__((ext_vector_type(4))) float f4v;
typedef __attribute__((ext_vector_type(8))) short s8v;
typedef __attribute__((ext_vector_type(4))) unsigned short us4;
typedef __attribute__((ext_vector_type(4))) unsigned int u32x4;

__device__ __forceinline__ u16 f2bf(float f) {
  union { float f; unsigned int u; } c; c.f = f;
  unsigned int u = c.u;
  unsigned int r = (u + 0x7FFFu + ((u >> 16) & 1u)) >> 16;
  return (u16)r;
}

// ---------------- gating: logits -> softmax -> top2 -> lists ----------------
__global__ __launch_bounds__(256) void gating_kernel(
    const float* __restrict__ x, const float* __restrict__ Wg,
    const float* __restrict__ bg, int* __restrict__ counts,
    int* __restrict__ lists, float* __restrict__ wslot)
{
  int wave = threadIdx.x >> 6, lane = threadIdx.x & 63;
  int n = blockIdx.x * 4 + wave;
  float acc[NE] = {0.f,0.f,0.f,0.f,0.f,0.f,0.f,0.f};
  const float4* x4 = reinterpret_cast<const float4*>(x + (size_t)n * DIM);
  #pragma unroll
  for (int i = 0; i < 8; ++i) {
    int d4 = lane + 64 * i;              // float4 index, 0..511
    float4 xv = x4[d4];
    float xs[4] = {xv.x, xv.y, xv.z, xv.w};
    const float4* wr = reinterpret_cast<const float4*>(Wg + (size_t)(d4 * 4) * NE);
    #pragma unroll
    for (int r = 0; r < 4; ++r) {
      float4 w0 = wr[r * 2 + 0], w1 = wr[r * 2 + 1];
      acc[0] += xs[r] * w0.x; acc[1] += xs[r] * w0.y;
      acc[2] += xs[r] * w0.z; acc[3] += xs[r] * w0.w;
      acc[4] += xs[r] * w1.x; acc[5] += xs[r] * w1.y;
      acc[6] += xs[r] * w1.z; acc[7] += xs[r] * w1.w;
    }
  }
  #pragma unroll
  for (int e = 0; e < NE; ++e)
    #pragma unroll
    for (int off = 32; off; off >>= 1)
      acc[e] += __shfl_xor(acc[e], off);

  if (lane == 0) {
    float m = -1e30f;
    #pragma unroll
    for (int e = 0; e < NE; ++e) { acc[e] += bg[e]; m = fmaxf(m, acc[e]); }
    float p[NE]; float s = 0.f;
    #pragma unroll
    for (int e = 0; e < NE; ++e) { p[e] = expf(acc[e] - m); s += p[e]; }
    float inv = 1.0f / s;
    int e1 = 0; float v1 = p[0];
    #pragma unroll
    for (int e = 1; e < NE; ++e) if (p[e] > v1) { v1 = p[e]; e1 = e; }
    int e2 = -1; float v2 = -1.f;
    #pragma unroll
    for (int e = 0; e < NE; ++e) if (e != e1 && p[e] > v2) { v2 = p[e]; e2 = e; }
    v1 *= inv; v2 *= inv;
    int pos1 = atomicAdd(&counts[e1], 1);
    lists[e1 * N_TOK + pos1] = n;
    wslot[n] = v1;
    int pos2 = atomicAdd(&counts[NE + e2], 1);
    lists[(NE + e2) * N_TOK + pos2] = n;
    wslot[N_TOK + n] = v2;
  }
}

// ---------------- prepass: x f32 -> bf16 ----------------
__global__ __launch_bounds__(256) void cvt_x_kernel(const float* __restrict__ xin,
                                                    u16* __restrict__ xb)
{
  const float4* in4 = reinterpret_cast<const float4*>(xin);
  const int total = N_TOK * DIM / 4;
  for (int idx = blockIdx.x * 256 + threadIdx.x; idx < total; idx += 2048 * 256) {
    float4 v = in4[idx];
    us4 u = {f2bf(v.x), f2bf(v.y), f2bf(v.z), f2bf(v.w)};
    reinterpret_cast<us4*>(xb)[idx] = u;
  }
}

// ---------------- prepass: We [e][k][h] f32 -> WeT [e][h][k] bf16 ----------------
__global__ __launch_bounds__(256) void transpose_we_kernel(const float* __restrict__ We,
                                                           u16* __restrict__ WeT)
{
  __shared__ u16 tile[64][72];  // +8 pad
  int e = blockIdx.z;
  int k0 = blockIdx.y * 64;
  int h0 = blockIdx.x * 64;
  const float* src = We + (size_t)e * DIM * HID + (size_t)k0 * HID + h0;
  #pragma unroll
  for (int i = 0; i < 4; ++i) {
    int flat = threadIdx.x + 256 * i;   // 0..1023
    int kk = flat >> 4, c4 = flat & 15;
    float4 v = *reinterpret_cast<const float4*>(src + (size_t)kk * HID + c4 * 4);
    us4 u = {f2bf(v.x), f2bf(v.y), f2bf(v.z), f2bf(v.w)};
    *reinterpret_cast<us4*>(&tile[kk][c4 * 4]) = u;
  }
  __syncthreads();
  u16* dst = WeT + (size_t)e * HID * DIM + (size_t)h0 * DIM + k0;
  #pragma unroll
  for (int i = 0; i < 4; ++i) {
    int flat = threadIdx.x + 256 * i;
    int hh = flat >> 4, c4 = flat & 15;  // c4 -> k-chunk
    us4 u = {tile[c4 * 4 + 0][hh], tile[c4 * 4 + 1][hh],
             tile[c4 * 4 + 2][hh], tile[c4 * 4 + 3][hh]};
    *reinterpret_cast<us4*>(dst + (size_t)hh * DIM + c4 * 4) = u;
  }
}

// ---------------- GEMM core ----------------
__device__ __forceinline__ void mma_step(const u16* A_lds, const u16* B_lds,
                                         int lane, int wm, int wn, f4v acc[4][4])
{
  int lrow = lane & 15, lkg = lane >> 4;
  #pragma unroll
  for (int kk2 = 0; kk2 < 2; ++kk2) {
    s8v a[4], b[4];
    unsigned int koff = (unsigned int)(kk2 * 64 + lkg * 16);
    #pragma unroll
    for (int i = 0; i < 4; ++i) {
      unsigned int arow = (unsigned int)(wm + i * 16 + lrow);
      a[i] = *reinterpret_cast<const s8v*>(
          reinterpret_cast<const char*>(A_lds) + ((arow * 128u + koff) ^ ((arow & 7u) << 4)));
      unsigned int brow = (unsigned int)(wn + i * 16 + lrow);
      b[i] = *reinterpret_cast<const s8v*>(
          reinterpret_cast<const char*>(B_lds) + ((brow * 128u + koff) ^ ((brow & 7u) << 4)));
    }
    #pragma unroll
    for (int mi = 0; mi < 4; ++mi)
      #pragma unroll
      for (int ni = 0; ni < 4; ++ni)
        acc[mi][ni] = __builtin_amdgcn_mfma_f32_16x16x32_bf16(a[mi], b[ni], acc[mi][ni], 0, 0, 0);
  }
}

template <int PHASE, bool BF16SRC>
__global__ __launch_bounds__(256) void moe_gemm(
    const void* __restrict__ Asrc, const void* __restrict__ Bsrc,
    const float* __restrict__ be, const int* __restrict__ counts,
    const int* __restrict__ lists, const float* __restrict__ wslot,
    float* __restrict__ out)
{
  __shared__ __align__(16) u16 A_lds[128 * 64];
  __shared__ __align__(16) u16 B_lds[128 * 64];
  __shared__ int   tok_lds[128];
  __shared__ float wgt_lds[128];

  const int ntile = blockIdx.x;          // 0..15
  const int e  = blockIdx.y >> 6;        // 0..7
  const int mt = blockIdx.y & 63;        // 0..63
  const int cnt = counts[PHASE * NE + e];
  if (mt * 128 >= cnt) return;

  const int t = threadIdx.x;
  if (t < 128) {
    int r = mt * 128 + t;
    int rc = (r < cnt) ? r : (cnt - 1);
    int tok = lists[(PHASE * NE + e) * N_TOK + rc];
    tok_lds[t] = tok;
    wgt_lds[t] = wslot[PHASE * N_TOK + tok];
  }
  __syncthreads();

  const int lane = t & 63, wid = t >> 6;
  const int wm = (wid & 1) * 64, wn = (wid >> 1) * 64;

  f4v acc[4][4];
  f4v zero = {0.f, 0.f, 0.f, 0.f};
  #pragma unroll
  for (int mi = 0; mi < 4; ++mi)
    #pragma unroll
    for (int ni = 0; ni < 4; ++ni) acc[mi][ni] = zero;

  if constexpr (!BF16SRC) {
    const float* xf  = reinterpret_cast<const float*>(Asrc);
    const float* wef = reinterpret_cast<const float*>(Bsrc) + (size_t)e * DIM * HID;
    const float* ap[8]; unsigned int ab[8];
    #pragma unroll
    for (int i = 0; i < 8; ++i) {
      int flat = t + 256 * i;             // 0..2047
      int row = flat >> 4, c4 = flat & 15;
      ap[i] = xf + (size_t)tok_lds[row] * DIM + c4 * 4;
      ab[i] = ((unsigned int)(row * 128 + c4 * 8)) ^ (((unsigned int)row & 7u) << 4);
    }
    int bn = t & 127, bh = t >> 7;
    const float* bp0 = wef + (size_t)(bh * 32) * HID + ntile * 128 + bn;
    unsigned int nswz = (((unsigned int)bn & 7u) << 4);
    for (int kt = 0; kt < DIM / 64; ++kt) {
      #pragma unroll
      for (int i = 0; i < 8; ++i) {
        float4 v = *reinterpret_cast<const float4*>(ap[i] + kt * 64);
        us4 u = {f2bf(v.x), f2bf(v.y), f2bf(v.z), f2bf(v.w)};
        *reinterpret_cast<us4*>(reinterpret_cast<char*>(A_lds) + ab[i]) = u;
      }
      const float* bp = bp0 + (size_t)(kt * 64) * HID;
      #pragma unroll
      for (int kb = 0; kb < 8; ++kb) {
        float f0 = bp[(kb * 4 + 0) * HID];
        float f1 = bp[(kb * 4 + 1) * HID];
        float f2 = bp[(kb * 4 + 2) * HID];
        float f3 = bp[(kb * 4 + 3) * HID];
        us4 u = {f2bf(f0), f2bf(f1), f2bf(f2), f2bf(f3)};
        unsigned int byte = ((unsigned int)(bn * 128 + bh * 64 + kb * 8)) ^ nswz;
        *reinterpret_cast<us4*>(reinterpret_cast<char*>(B_lds) + byte) = u;
      }
      __syncthreads();
      mma_step(A_lds, B_lds, lane, wm, wn, acc);
      __syncthreads();
    }
  } else {
    const u16* xb  = reinterpret_cast<const u16*>(Asrc);
    const u16* web = reinterpret_cast<const u16*>(Bsrc) + (size_t)e * DIM * HID;
    const u16* ap[4]; const u16* bp[4]; unsigned int ab[4];
    #pragma unroll
    for (int i = 0; i < 4; ++i) {
      int flat = t + 256 * i;             // 0..1023
      int row = flat >> 3, c8 = flat & 7;
      ap[i] = xb + (size_t)tok_lds[row] * DIM + c8 * 8;
      bp[i] = web + (size_t)(ntile * 128 + row) * DIM + c8 * 8;
      ab[i] = ((unsigned int)(row * 128 + c8 * 16)) ^ (((unsigned int)row & 7u) << 4);
    }
    for (int kt = 0; kt < DIM / 64; ++kt) {
      #pragma unroll
      for (int i = 0; i < 4; ++i) {
        u32x4 va = *reinterpret_cast<const u32x4*>(ap[i] + kt * 64);
        *reinterpret_cast<u32x4*>(reinterpret_cast<char*>(A_lds) + ab[i]) = va;
        u32x4 vb = *reinterpret_cast<const u32x4*>(bp[i] + kt * 64);
        *reinterpret_cast<u32x4*>(reinterpret_cast<char*>(B_lds) + ab[i]) = vb;
      }
      __syncthreads();
      mma_step(A_lds, B_lds, lane, wm, wn, acc);
      __syncthreads();
    }
  }

  // epilogue: D row=(lane>>4)*4+q (A/m), col=lane&15 (B/n)  [m89-verified]
  const float* bev = be + (size_t)e * HID + ntile * 128;
  #pragma unroll
  for (int ni = 0; ni < 4; ++ni) {
    int col = wn + ni * 16 + (lane & 15);
    float bevv = bev[col];
    #pragma unroll
    for (int mi = 0; mi < 4; ++mi) {
      #pragma unroll
      for (int q = 0; q < 4; ++q) {
        int row = wm + mi * 16 + (lane >> 4) * 4 + q;
        if (mt * 128 + row < cnt) {
          int tok = tok_lds[row];
          float w = wgt_lds[row];
          float v = w * (acc[mi][ni][q] + bevv);
          float* o = out + (size_t)tok * HID + ntile * 128 + col;
          if (PHASE == 0) *o = v; else *o += v;
        }
      }
    }
  }
}

// ---------------- host ----------------
extern "C" void kernel_launch(void* const* d_in, const int* in_sizes, int n_in,
                              void* d_out, int out_size, void* d_ws, size_t ws_size,
                              hipStream_t stream) {
  const float* x  = (const float*)d_in[0];
  const float* Wg = (const float*)d_in[1];
  const float* bg = (const float*)d_in[2];
  const float* We = (const float*)d_in[3];
  const float* be = (const float*)d_in[4];
  float* out = (float*)d_out;
  char* ws = (char*)d_ws;

  int*   counts = (int*)ws;                                   // 16 ints
  float* wslot  = (float*)(ws + 256);                         // 2*8192 f32
  int*   lists  = (int*)(ws + 256 + sizeof(float) * 2 * N_TOK); // 2*8*8192 int
  size_t small_end = 256 + sizeof(float) * 2 * N_TOK + sizeof(int) * 2 * NE * N_TOK;
  size_t off_x = (small_end + 255) & ~(size_t)255;
  size_t xbytes = (size_t)N_TOK * DIM * 2;
  size_t off_w = off_x + xbytes;
  size_t wbytes = (size_t)NE * DIM * HID * 2;
  bool full = (ws_size >= off_w + wbytes);

  hipMemsetAsync(counts, 0, 2 * NE * sizeof(int), stream);
  hipLaunchKernelGGL(gating_kernel, dim3(N_TOK / 4), dim3(256), 0, stream,
                     x, Wg, bg, counts, lists, wslot);

  dim3 ggrid(HID / 128, NE * (N_TOK / 128));
  if (full) {
    u16* xb = (u16*)(ws + off_x);
    u16* wt = (u16*)(ws + off_w);
    hipLaunchKernelGGL(cvt_x_kernel, dim3(2048), dim3(256), 0, stream, x, xb);
    hipLaunchKernelGGL(transpose_we_kernel, dim3(HID / 64, DIM / 64, NE), dim3(256), 0, stream, We, wt);
    hipLaunchKernelGGL((moe_gemm<0, true>), ggrid, dim3(256), 0, stream,
                       (const void*)xb, (const void*)wt, be, counts, lists, wslot, out);
    hipLaunchKernelGGL((moe_gemm<1, true>), ggrid, dim3(256), 0, stream,
                       (const void*)xb, (const void*)wt, be, counts, lists, wslot, out);
  } else {
    hipLaunchKernelGGL((moe_gemm<0, false>), ggrid, dim3(256), 0, stream,
                       (const void*)x, (const void*)We, be, counts, lists, wslot, out);
    hipLaunchKernelGGL((moe_gemm<1, false>), ggrid, dim3(256), 0, stream,
                       (const void*)x, (const void*)We, be, counts, lists, wslot, out);
  }
}

// Round 2
// 598.693 us; speedup vs baseline: 1.0083x; 1.0083x over previous
//
#include <hip/hip_runtime.h>

#define N_TOK 8192
#define DIM   2048
#define HID   2048
#define NE    8

typedef unsigned short u16;
typedef __attribute__((ext_vector_type(4))) float f4v;
typedef __attribute__((ext_vector_type(8))) short s8v;
typedef __attribute__((ext_vector_type(4))) unsigned short us4;
typedef __attribute__((ext_vector_type(4))) unsigned int u32x4;

__device__ __forceinline__ u16 f2bf(float f) {
  union { float f; unsigned int u; } c; c.f = f;
  unsigned int u = c.u;
  unsigned int r = (u + 0x7FFFu + ((u >> 16) & 1u)) >> 16;
  return (u16)r;
}

__device__ __forceinline__ void gll16(const void* g, void* l) {
  __builtin_amdgcn_global_load_lds(
      (const __attribute__((address_space(1))) void*)g,
      (__attribute__((address_space(3))) void*)l, 16, 0, 0);
}

// ---------------- gating: logits -> softmax -> top2 -> lists (+ x->bf16) ----------------
// 256 blocks x 32 tokens. Wg staged transposed in LDS [e][d] f32 (64 KB).
__global__ __launch_bounds__(256) void gating_kernel(
    const float* __restrict__ x, const float* __restrict__ Wg,
    const float* __restrict__ bg, int* __restrict__ counts,
    int* __restrict__ lists, float* __restrict__ wslot,
    u16* __restrict__ xb)
{
  __shared__ float wg_lds[NE][DIM];   // 64 KB
  // coalesced load of Wg [d][e] -> LDS [e][d]
  #pragma unroll
  for (int i = 0; i < 16; ++i) {
    int f = threadIdx.x + 256 * i;          // float4 index 0..4095
    int d = f >> 1, ep = (f & 1) * 4;
    float4 w = reinterpret_cast<const float4*>(Wg)[f];
    wg_lds[ep + 0][d] = w.x; wg_lds[ep + 1][d] = w.y;
    wg_lds[ep + 2][d] = w.z; wg_lds[ep + 3][d] = w.w;
  }
  __syncthreads();

  int wave = threadIdx.x >> 6, lane = threadIdx.x & 63;
  #pragma unroll 1
  for (int j = 0; j < 8; ++j) {
    int n = blockIdx.x * 32 + wave * 8 + j;
    const float4* x4 = reinterpret_cast<const float4*>(x + (size_t)n * DIM);
    float acc[NE] = {0.f,0.f,0.f,0.f,0.f,0.f,0.f,0.f};
    #pragma unroll
    for (int i = 0; i < 8; ++i) {
      int d4 = lane + 64 * i;
      float4 xv = x4[d4];
      if (xb) {
        us4 u = {f2bf(xv.x), f2bf(xv.y), f2bf(xv.z), f2bf(xv.w)};
        *reinterpret_cast<us4*>(xb + (size_t)n * DIM + d4 * 4) = u;
      }
      #pragma unroll
      for (int e = 0; e < NE; ++e) {
        float4 w = *reinterpret_cast<const float4*>(&wg_lds[e][d4 * 4]);
        acc[e] += xv.x * w.x + xv.y * w.y + xv.z * w.z + xv.w * w.w;
      }
    }
    #pragma unroll
    for (int e = 0; e < NE; ++e)
      #pragma unroll
      for (int off = 32; off; off >>= 1)
        acc[e] += __shfl_xor(acc[e], off);

    if (lane == 0) {
      float m = -1e30f;
      #pragma unroll
      for (int e = 0; e < NE; ++e) { acc[e] += bg[e]; m = fmaxf(m, acc[e]); }
      float p[NE]; float s = 0.f;
      #pragma unroll
      for (int e = 0; e < NE; ++e) { p[e] = expf(acc[e] - m); s += p[e]; }
      float inv = 1.0f / s;
      int e1 = 0; float v1 = p[0];
      #pragma unroll
      for (int e = 1; e < NE; ++e) if (p[e] > v1) { v1 = p[e]; e1 = e; }
      int e2 = -1; float v2 = -1.f;
      #pragma unroll
      for (int e = 0; e < NE; ++e) if (e != e1 && p[e] > v2) { v2 = p[e]; e2 = e; }
      v1 *= inv; v2 *= inv;
      int pos1 = atomicAdd(&counts[e1], 1);
      lists[e1 * N_TOK + pos1] = n;
      wslot[n] = v1;
      int pos2 = atomicAdd(&counts[NE + e2], 1);
      lists[(NE + e2) * N_TOK + pos2] = n;
      wslot[N_TOK + n] = v2;
    }
  }
}

// ---------------- prepass: We [e][k][h] f32 -> WeT [e][h][k] bf16 ----------------
__global__ __launch_bounds__(256) void transpose_we_kernel(const float* __restrict__ We,
                                                           u16* __restrict__ WeT)
{
  __shared__ u16 tile[64][72];  // +8 pad
  int e = blockIdx.z;
  int k0 = blockIdx.y * 64;
  int h0 = blockIdx.x * 64;
  const float* src = We + (size_t)e * DIM * HID + (size_t)k0 * HID + h0;
  #pragma unroll
  for (int i = 0; i < 4; ++i) {
    int flat = threadIdx.x + 256 * i;   // 0..1023
    int kk = flat >> 4, c4 = flat & 15;
    float4 v = *reinterpret_cast<const float4*>(src + (size_t)kk * HID + c4 * 4);
    us4 u = {f2bf(v.x), f2bf(v.y), f2bf(v.z), f2bf(v.w)};
    *reinterpret_cast<us4*>(&tile[kk][c4 * 4]) = u;
  }
  __syncthreads();
  u16* dst = WeT + (size_t)e * HID * DIM + (size_t)h0 * DIM + k0;
  #pragma unroll
  for (int i = 0; i < 4; ++i) {
    int flat = threadIdx.x + 256 * i;
    int hh = flat >> 4, c4 = flat & 15;  // c4 -> k-chunk
    us4 u = {tile[c4 * 4 + 0][hh], tile[c4 * 4 + 1][hh],
             tile[c4 * 4 + 2][hh], tile[c4 * 4 + 3][hh]};
    *reinterpret_cast<us4*>(dst + (size_t)hh * DIM + c4 * 4) = u;
  }
}

// ---------------- GEMM core ----------------
__device__ __forceinline__ void mma_step(const u16* A_lds, const u16* B_lds,
                                         int lane, int wm, int wn, f4v acc[4][4])
{
  int lrow = lane & 15, lkg = lane >> 4;
  #pragma unroll
  for (int kk2 = 0; kk2 < 2; ++kk2) {
    s8v a[4], b[4];
    unsigned int koff = (unsigned int)(kk2 * 64 + lkg * 16);
    #pragma unroll
    for (int i = 0; i < 4; ++i) {
      unsigned int arow = (unsigned int)(wm + i * 16 + lrow);
      a[i] = *reinterpret_cast<const s8v*>(
          reinterpret_cast<const char*>(A_lds) + ((arow * 128u + koff) ^ ((arow & 7u) << 4)));
      unsigned int brow = (unsigned int)(wn + i * 16 + lrow);
      b[i] = *reinterpret_cast<const s8v*>(
          reinterpret_cast<const char*>(B_lds) + ((brow * 128u + koff) ^ ((brow & 7u) << 4)));
    }
    #pragma unroll
    for (int mi = 0; mi < 4; ++mi)
      #pragma unroll
      for (int ni = 0; ni < 4; ++ni)
        acc[mi][ni] = __builtin_amdgcn_mfma_f32_16x16x32_bf16(a[mi], b[ni], acc[mi][ni], 0, 0, 0);
  }
}

template <int PHASE, bool BF16SRC>
__global__ __launch_bounds__(256) void moe_gemm(
    const void* __restrict__ Asrc, const void* __restrict__ Bsrc,
    const float* __restrict__ be, const int* __restrict__ counts,
    const int* __restrict__ lists, const float* __restrict__ wslot,
    float* __restrict__ out)
{
  __shared__ __align__(16) u16 A_lds[128 * 64];
  __shared__ __align__(16) u16 B_lds[128 * 64];
  __shared__ int   tok_lds[128];
  __shared__ float wgt_lds[128];

  const int ntile = blockIdx.x;          // 0..15
  const int e  = blockIdx.y >> 6;        // 0..7
  const int mt = blockIdx.y & 63;        // 0..63
  const int cnt = counts[PHASE * NE + e];
  if (mt * 128 >= cnt) return;

  const int t = threadIdx.x;
  if (t < 128) {
    int r = mt * 128 + t;
    int rc = (r < cnt) ? r : (cnt - 1);
    int tok = lists[(PHASE * NE + e) * N_TOK + rc];
    tok_lds[t] = tok;
    wgt_lds[t] = wslot[PHASE * N_TOK + tok];
  }
  __syncthreads();

  const int lane = t & 63, wid = t >> 6;
  const int wm = (wid & 1) * 64, wn = (wid >> 1) * 64;

  f4v acc[4][4];
  f4v zero = {0.f, 0.f, 0.f, 0.f};
  #pragma unroll
  for (int mi = 0; mi < 4; ++mi)
    #pragma unroll
    for (int ni = 0; ni < 4; ++ni) acc[mi][ni] = zero;

  if constexpr (!BF16SRC) {
    const float* xf  = reinterpret_cast<const float*>(Asrc);
    const float* wef = reinterpret_cast<const float*>(Bsrc) + (size_t)e * DIM * HID;
    const float* ap[8]; unsigned int ab[8];
    #pragma unroll
    for (int i = 0; i < 8; ++i) {
      int flat = t + 256 * i;             // 0..2047
      int row = flat >> 4, c4 = flat & 15;
      ap[i] = xf + (size_t)tok_lds[row] * DIM + c4 * 4;
      ab[i] = ((unsigned int)(row * 128 + c4 * 8)) ^ (((unsigned int)row & 7u) << 4);
    }
    int bn = t & 127, bh = t >> 7;
    const float* bp0 = wef + (size_t)(bh * 32) * HID + ntile * 128 + bn;
    unsigned int nswz = (((unsigned int)bn & 7u) << 4);
    for (int kt = 0; kt < DIM / 64; ++kt) {
      #pragma unroll
      for (int i = 0; i < 8; ++i) {
        float4 v = *reinterpret_cast<const float4*>(ap[i] + kt * 64);
        us4 u = {f2bf(v.x), f2bf(v.y), f2bf(v.z), f2bf(v.w)};
        *reinterpret_cast<us4*>(reinterpret_cast<char*>(A_lds) + ab[i]) = u;
      }
      const float* bp = bp0 + (size_t)(kt * 64) * HID;
      #pragma unroll
      for (int kb = 0; kb < 8; ++kb) {
        float f0 = bp[(kb * 4 + 0) * HID];
        float f1 = bp[(kb * 4 + 1) * HID];
        float f2 = bp[(kb * 4 + 2) * HID];
        float f3 = bp[(kb * 4 + 3) * HID];
        us4 u = {f2bf(f0), f2bf(f1), f2bf(f2), f2bf(f3)};
        unsigned int byte = ((unsigned int)(bn * 128 + bh * 64 + kb * 8)) ^ nswz;
        *reinterpret_cast<us4*>(reinterpret_cast<char*>(B_lds) + byte) = u;
      }
      __syncthreads();
      mma_step(A_lds, B_lds, lane, wm, wn, acc);
      __syncthreads();
    }
  } else {
    // global_load_lds staging: linear LDS dest, pre-swizzled global source.
    const u16* xbp = reinterpret_cast<const u16*>(Asrc);
    const u16* web = reinterpret_cast<const u16*>(Bsrc) + (size_t)e * DIM * HID;
    const int r8 = lane >> 3;                       // row within 8-row group
    const unsigned int ssw = ((unsigned int)((lane & 7) ^ r8)) << 4;  // source k-chunk
    const char* srcA[4]; const char* srcB[4];
    #pragma unroll
    for (int i = 0; i < 4; ++i) {
      int row = wid * 32 + i * 8 + r8;              // 0..127, each exactly once
      srcA[i] = reinterpret_cast<const char*>(xbp + (size_t)tok_lds[row] * DIM) + ssw;
      srcB[i] = reinterpret_cast<const char*>(web + (size_t)(ntile * 128 + row) * DIM) + ssw;
    }
    for (int kt = 0; kt < DIM / 64; ++kt) {
      #pragma unroll
      for (int i = 0; i < 4; ++i) {
        gll16(srcA[i] + kt * 128, reinterpret_cast<char*>(A_lds) + wid * 4096 + i * 1024);
        gll16(srcB[i] + kt * 128, reinterpret_cast<char*>(B_lds) + wid * 4096 + i * 1024);
      }
      __syncthreads();
      mma_step(A_lds, B_lds, lane, wm, wn, acc);
      __syncthreads();
    }
  }

  // epilogue: D row=(lane>>4)*4+q (A/m), col=lane&15 (B/n)  [m89-verified]
  const float* bev = be + (size_t)e * HID + ntile * 128;
  #pragma unroll
  for (int ni = 0; ni < 4; ++ni) {
    int col = wn + ni * 16 + (lane & 15);
    float bevv = bev[col];
    #pragma unroll
    for (int mi = 0; mi < 4; ++mi) {
      #pragma unroll
      for (int q = 0; q < 4; ++q) {
        int row = wm + mi * 16 + (lane >> 4) * 4 + q;
        if (mt * 128 + row < cnt) {
          int tok = tok_lds[row];
          float w = wgt_lds[row];
          float v = w * (acc[mi][ni][q] + bevv);
          float* o = out + (size_t)tok * HID + ntile * 128 + col;
          if (PHASE == 0) *o = v; else *o += v;
        }
      }
    }
  }
}

// ---------------- host ----------------
extern "C" void kernel_launch(void* const* d_in, const int* in_sizes, int n_in,
                              void* d_out, int out_size, void* d_ws, size_t ws_size,
                              hipStream_t stream) {
  const float* x  = (const float*)d_in[0];
  const float* Wg = (const float*)d_in[1];
  const float* bg = (const float*)d_in[2];
  const float* We = (const float*)d_in[3];
  const float* be = (const float*)d_in[4];
  float* out = (float*)d_out;
  char* ws = (char*)d_ws;

  int*   counts = (int*)ws;                                   // 16 ints
  float* wslot  = (float*)(ws + 256);                         // 2*8192 f32
  int*   lists  = (int*)(ws + 256 + sizeof(float) * 2 * N_TOK); // 2*8*8192 int
  size_t small_end = 256 + sizeof(float) * 2 * N_TOK + sizeof(int) * 2 * NE * N_TOK;
  size_t off_x = (small_end + 255) & ~(size_t)255;
  size_t xbytes = (size_t)N_TOK * DIM * 2;
  size_t off_w = off_x + xbytes;
  size_t wbytes = (size_t)NE * DIM * HID * 2;
  bool full = (ws_size >= off_w + wbytes);

  u16* xb = full ? (u16*)(ws + off_x) : nullptr;

  hipMemsetAsync(counts, 0, 2 * NE * sizeof(int), stream);
  hipLaunchKernelGGL(gating_kernel, dim3(256), dim3(256), 0, stream,
                     x, Wg, bg, counts, lists, wslot, xb);

  dim3 ggrid(HID / 128, NE * (N_TOK / 128));
  if (full) {
    u16* wt = (u16*)(ws + off_w);
    hipLaunchKernelGGL(transpose_we_kernel, dim3(HID / 64, DIM / 64, NE), dim3(256), 0, stream, We, wt);
    hipLaunchKernelGGL((moe_gemm<0, true>), ggrid, dim3(256), 0, stream,
                       (const void*)xb, (const void*)wt, be, counts, lists, wslot, out);
    hipLaunchKernelGGL((moe_gemm<1, true>), ggrid, dim3(256), 0, stream,
                       (const void*)xb, (const void*)wt, be, counts, lists, wslot, out);
  } else {
    hipLaunchKernelGGL((moe_gemm<0, false>), ggrid, dim3(256), 0, stream,
                       (const void*)x, (const void*)We, be, counts, lists, wslot, out);
    hipLaunchKernelGGL((moe_gemm<1, false>), ggrid, dim3(256), 0, stream,
                       (const void*)x, (const void*)We, be, counts, lists, wslot, out);
  }
}

// Round 3
// 450.236 us; speedup vs baseline: 1.3408x; 1.3297x over previous
//
#include <hip/hip_runtime.h>

#define N_TOK 8192
#define DIM   2048
#define HID   2048
#define NE    8

typedef unsigned short u16;
typedef __attribute__((ext_vector_type(4))) float f4v;
typedef __attribute__((ext_vector_type(8))) short s8v;
typedef __attribute__((ext_vector_type(4))) unsigned short us4;
typedef __attribute__((ext_vector_type(4))) unsigned int u32x4;

__device__ __forceinline__ u16 f2bf(float f) {
  union { float f; unsigned int u; } c; c.f = f;
  unsigned int u = c.u;
  unsigned int r = (u + 0x7FFFu + ((u >> 16) & 1u)) >> 16;
  return (u16)r;
}

__device__ __forceinline__ void gll16(const void* g, void* l) {
  __builtin_amdgcn_global_load_lds(
      (const __attribute__((address_space(1))) void*)g,
      (__attribute__((address_space(3))) void*)l, 16, 0, 0);
}

// ---------------- gating: logits -> softmax -> top2 (NO atomics) + x->bf16 ----------------
// 512 blocks x 16 tokens. Wg staged transposed in LDS [e][d] f32 (64 KB).
__global__ __launch_bounds__(256) void gating_kernel(
    const float* __restrict__ x, const float* __restrict__ Wg,
    const float* __restrict__ bg, int* __restrict__ sel,
    float* __restrict__ wslot, u16* __restrict__ xb)
{
  __shared__ float wg_lds[NE][DIM];   // 64 KB
  #pragma unroll
  for (int i = 0; i < 16; ++i) {
    int f = threadIdx.x + 256 * i;          // float4 index 0..4095
    int d = f >> 1, ep = (f & 1) * 4;
    float4 w = reinterpret_cast<const float4*>(Wg)[f];
    wg_lds[ep + 0][d] = w.x; wg_lds[ep + 1][d] = w.y;
    wg_lds[ep + 2][d] = w.z; wg_lds[ep + 3][d] = w.w;
  }
  __syncthreads();

  int wave = threadIdx.x >> 6, lane = threadIdx.x & 63;
  #pragma unroll 2
  for (int j = 0; j < 4; ++j) {
    int n = blockIdx.x * 16 + wave * 4 + j;
    const float4* x4 = reinterpret_cast<const float4*>(x + (size_t)n * DIM);
    float acc[NE] = {0.f,0.f,0.f,0.f,0.f,0.f,0.f,0.f};
    #pragma unroll
    for (int i = 0; i < 8; ++i) {
      int d4 = lane + 64 * i;
      float4 xv = x4[d4];
      if (xb) {
        us4 u = {f2bf(xv.x), f2bf(xv.y), f2bf(xv.z), f2bf(xv.w)};
        *reinterpret_cast<us4*>(xb + (size_t)n * DIM + d4 * 4) = u;
      }
      #pragma unroll
      for (int e = 0; e < NE; ++e) {
        float4 w = *reinterpret_cast<const float4*>(&wg_lds[e][d4 * 4]);
        acc[e] += xv.x * w.x + xv.y * w.y + xv.z * w.z + xv.w * w.w;
      }
    }
    #pragma unroll
    for (int e = 0; e < NE; ++e)
      #pragma unroll
      for (int off = 32; off; off >>= 1)
        acc[e] += __shfl_xor(acc[e], off);

    if (lane == 0) {
      float m = -1e30f;
      #pragma unroll
      for (int e = 0; e < NE; ++e) { acc[e] += bg[e]; m = fmaxf(m, acc[e]); }
      float p[NE]; float s = 0.f;
      #pragma unroll
      for (int e = 0; e < NE; ++e) { p[e] = expf(acc[e] - m); s += p[e]; }
      float inv = 1.0f / s;
      int e1 = 0; float v1 = p[0];
      #pragma unroll
      for (int e = 1; e < NE; ++e) if (p[e] > v1) { v1 = p[e]; e1 = e; }
      int e2 = -1; float v2 = -1.f;
      #pragma unroll
      for (int e = 0; e < NE; ++e) if (e != e1 && p[e] > v2) { v2 = p[e]; e2 = e; }
      sel[n] = e1 | (e2 << 4);
      wslot[n] = v1 * inv;
      wslot[N_TOK + n] = v2 * inv;
    }
  }
}

// ---------------- build per-(slot,expert) token lists: deterministic compaction ----------------
__global__ __launch_bounds__(256) void build_lists_kernel(
    const int* __restrict__ sel, int* __restrict__ counts, int* __restrict__ lists)
{
  __shared__ int wsum[4];
  __shared__ int runbase;
  int b = blockIdx.x;           // 0..15: slot = b>>3, expert = b&7
  int s = b >> 3, e = b & 7;
  int t = threadIdx.x, lane = t & 63, wave = t >> 6;
  if (t == 0) runbase = 0;
  __syncthreads();
  int* listp = lists + (size_t)b * N_TOK;
  for (int base = 0; base < N_TOK; base += 256) {
    int n = base + t;
    int sv = sel[n];
    int field = s ? (sv >> 4) : (sv & 15);
    bool p = (field == e);
    unsigned long long mask = __ballot(p);
    int rank = __popcll(mask & ((1ull << lane) - 1ull));
    int wtot = __popcll(mask);
    if (lane == 0) wsum[wave] = wtot;
    __syncthreads();
    int wbase = 0;
    #pragma unroll
    for (int w = 0; w < 4; ++w) wbase += (w < wave) ? wsum[w] : 0;
    int tot = wsum[0] + wsum[1] + wsum[2] + wsum[3];
    if (p) listp[runbase + wbase + rank] = n;
    __syncthreads();
    if (t == 0) runbase += tot;
    __syncthreads();
  }
  if (t == 0) counts[b] = runbase;
}

// ---------------- prepass: We [e][k][h] f32 -> WeT [e][h][k] bf16 ----------------
__global__ __launch_bounds__(256) void transpose_we_kernel(const float* __restrict__ We,
                                                           u16* __restrict__ WeT)
{
  __shared__ u16 tile[64][72];  // +8 pad
  int e = blockIdx.z;
  int k0 = blockIdx.y * 64;
  int h0 = blockIdx.x * 64;
  const float* src = We + (size_t)e * DIM * HID + (size_t)k0 * HID + h0;
  #pragma unroll
  for (int i = 0; i < 4; ++i) {
    int flat = threadIdx.x + 256 * i;   // 0..1023
    int kk = flat >> 4, c4 = flat & 15;
    float4 v = *reinterpret_cast<const float4*>(src + (size_t)kk * HID + c4 * 4);
    us4 u = {f2bf(v.x), f2bf(v.y), f2bf(v.z), f2bf(v.w)};
    *reinterpret_cast<us4*>(&tile[kk][c4 * 4]) = u;
  }
  __syncthreads();
  u16* dst = WeT + (size_t)e * HID * DIM + (size_t)h0 * DIM + k0;
  #pragma unroll
  for (int i = 0; i < 4; ++i) {
    int flat = threadIdx.x + 256 * i;
    int hh = flat >> 4, c4 = flat & 15;  // c4 -> k-chunk
    us4 u = {tile[c4 * 4 + 0][hh], tile[c4 * 4 + 1][hh],
             tile[c4 * 4 + 2][hh], tile[c4 * 4 + 3][hh]};
    *reinterpret_cast<us4*>(dst + (size_t)hh * DIM + c4 * 4) = u;
  }
}

// ---------------- GEMM core ----------------
__device__ __forceinline__ void mma_step(const u16* A_lds, const u16* B_lds,
                                         int lane, int wm, int wn, f4v acc[4][4])
{
  int lrow = lane & 15, lkg = lane >> 4;
  #pragma unroll
  for (int kk2 = 0; kk2 < 2; ++kk2) {
    s8v a[4], b[4];
    unsigned int koff = (unsigned int)(kk2 * 64 + lkg * 16);
    #pragma unroll
    for (int i = 0; i < 4; ++i) {
      unsigned int arow = (unsigned int)(wm + i * 16 + lrow);
      a[i] = *reinterpret_cast<const s8v*>(
          reinterpret_cast<const char*>(A_lds) + ((arow * 128u + koff) ^ ((arow & 7u) << 4)));
      unsigned int brow = (unsigned int)(wn + i * 16 + lrow);
      b[i] = *reinterpret_cast<const s8v*>(
          reinterpret_cast<const char*>(B_lds) + ((brow * 128u + koff) ^ ((brow & 7u) << 4)));
    }
    #pragma unroll
    for (int mi = 0; mi < 4; ++mi)
      #pragma unroll
      for (int ni = 0; ni < 4; ++ni)
        acc[mi][ni] = __builtin_amdgcn_mfma_f32_16x16x32_bf16(a[mi], b[ni], acc[mi][ni], 0, 0, 0);
  }
}

template <int PHASE, bool BF16SRC>
__global__ __launch_bounds__(256) void moe_gemm(
    const void* __restrict__ Asrc, const void* __restrict__ Bsrc,
    const float* __restrict__ be, const int* __restrict__ counts,
    const int* __restrict__ lists, const float* __restrict__ wslot,
    float* __restrict__ out)
{
  __shared__ __align__(16) u16 A_lds[128 * 64];
  __shared__ __align__(16) u16 B_lds[128 * 64];
  __shared__ int   tok_lds[128];
  __shared__ float wgt_lds[128];

  const int ntile = blockIdx.x;          // 0..15
  const int e  = blockIdx.y >> 6;        // 0..7
  const int mt = blockIdx.y & 63;        // 0..63
  const int cnt = counts[PHASE * NE + e];
  if (mt * 128 >= cnt) return;

  const int t = threadIdx.x;
  if (t < 128) {
    int r = mt * 128 + t;
    int rc = (r < cnt) ? r : (cnt - 1);
    int tok = lists[(PHASE * NE + e) * N_TOK + rc];
    tok_lds[t] = tok;
    wgt_lds[t] = wslot[PHASE * N_TOK + tok];
  }
  __syncthreads();

  const int lane = t & 63, wid = t >> 6;
  const int wm = (wid & 1) * 64, wn = (wid >> 1) * 64;

  f4v acc[4][4];
  f4v zero = {0.f, 0.f, 0.f, 0.f};
  #pragma unroll
  for (int mi = 0; mi < 4; ++mi)
    #pragma unroll
    for (int ni = 0; ni < 4; ++ni) acc[mi][ni] = zero;

  if constexpr (!BF16SRC) {
    const float* xf  = reinterpret_cast<const float*>(Asrc);
    const float* wef = reinterpret_cast<const float*>(Bsrc) + (size_t)e * DIM * HID;
    const float* ap[8]; unsigned int ab[8];
    #pragma unroll
    for (int i = 0; i < 8; ++i) {
      int flat = t + 256 * i;             // 0..2047
      int row = flat >> 4, c4 = flat & 15;
      ap[i] = xf + (size_t)tok_lds[row] * DIM + c4 * 4;
      ab[i] = ((unsigned int)(row * 128 + c4 * 8)) ^ (((unsigned int)row & 7u) << 4);
    }
    int bn = t & 127, bh = t >> 7;
    const float* bp0 = wef + (size_t)(bh * 32) * HID + ntile * 128 + bn;
    unsigned int nswz = (((unsigned int)bn & 7u) << 4);
    for (int kt = 0; kt < DIM / 64; ++kt) {
      #pragma unroll
      for (int i = 0; i < 8; ++i) {
        float4 v = *reinterpret_cast<const float4*>(ap[i] + kt * 64);
        us4 u = {f2bf(v.x), f2bf(v.y), f2bf(v.z), f2bf(v.w)};
        *reinterpret_cast<us4*>(reinterpret_cast<char*>(A_lds) + ab[i]) = u;
      }
      const float* bp = bp0 + (size_t)(kt * 64) * HID;
      #pragma unroll
      for (int kb = 0; kb < 8; ++kb) {
        float f0 = bp[(kb * 4 + 0) * HID];
        float f1 = bp[(kb * 4 + 1) * HID];
        float f2 = bp[(kb * 4 + 2) * HID];
        float f3 = bp[(kb * 4 + 3) * HID];
        us4 u = {f2bf(f0), f2bf(f1), f2bf(f2), f2bf(f3)};
        unsigned int byte = ((unsigned int)(bn * 128 + bh * 64 + kb * 8)) ^ nswz;
        *reinterpret_cast<us4*>(reinterpret_cast<char*>(B_lds) + byte) = u;
      }
      __syncthreads();
      mma_step(A_lds, B_lds, lane, wm, wn, acc);
      __syncthreads();
    }
  } else {
    // global_load_lds staging: linear LDS dest, pre-swizzled global source.
    const u16* xbp = reinterpret_cast<const u16*>(Asrc);
    const u16* web = reinterpret_cast<const u16*>(Bsrc) + (size_t)e * DIM * HID;
    const int r8 = lane >> 3;                       // row within 8-row group
    const unsigned int ssw = ((unsigned int)((lane & 7) ^ r8)) << 4;  // source k-chunk
    const char* srcA[4]; const char* srcB[4];
    #pragma unroll
    for (int i = 0; i < 4; ++i) {
      int row = wid * 32 + i * 8 + r8;              // 0..127, each exactly once
      srcA[i] = reinterpret_cast<const char*>(xbp + (size_t)tok_lds[row] * DIM) + ssw;
      srcB[i] = reinterpret_cast<const char*>(web + (size_t)(ntile * 128 + row) * DIM) + ssw;
    }
    for (int kt = 0; kt < DIM / 64; ++kt) {
      #pragma unroll
      for (int i = 0; i < 4; ++i) {
        gll16(srcA[i] + kt * 128, reinterpret_cast<char*>(A_lds) + wid * 4096 + i * 1024);
        gll16(srcB[i] + kt * 128, reinterpret_cast<char*>(B_lds) + wid * 4096 + i * 1024);
      }
      __syncthreads();
      mma_step(A_lds, B_lds, lane, wm, wn, acc);
      __syncthreads();
    }
  }

  // epilogue: D row=(lane>>4)*4+q (A/m), col=lane&15 (B/n)  [m89-verified]
  const float* bev = be + (size_t)e * HID + ntile * 128;
  #pragma unroll
  for (int ni = 0; ni < 4; ++ni) {
    int col = wn + ni * 16 + (lane & 15);
    float bevv = bev[col];
    #pragma unroll
    for (int mi = 0; mi < 4; ++mi) {
      #pragma unroll
      for (int q = 0; q < 4; ++q) {
        int row = wm + mi * 16 + (lane >> 4) * 4 + q;
        if (mt * 128 + row < cnt) {
          int tok = tok_lds[row];
          float w = wgt_lds[row];
          float v = w * (acc[mi][ni][q] + bevv);
          float* o = out + (size_t)tok * HID + ntile * 128 + col;
          if (PHASE == 0) *o = v; else *o += v;
        }
      }
    }
  }
}

// ---------------- host ----------------
extern "C" void kernel_launch(void* const* d_in, const int* in_sizes, int n_in,
                              void* d_out, int out_size, void* d_ws, size_t ws_size,
                              hipStream_t stream) {
  const float* x  = (const float*)d_in[0];
  const float* Wg = (const float*)d_in[1];
  const float* bg = (const float*)d_in[2];
  const float* We = (const float*)d_in[3];
  const float* be = (const float*)d_in[4];
  float* out = (float*)d_out;
  char* ws = (char*)d_ws;

  int*   counts = (int*)ws;                                   // 16 ints
  int*   sel    = (int*)(ws + 256);                           // 8192 ints
  float* wslot  = (float*)(ws + 256 + sizeof(int) * N_TOK);   // 2*8192 f32
  int*   lists  = (int*)(ws + 256 + sizeof(int) * N_TOK + sizeof(float) * 2 * N_TOK);
  size_t small_end = 256 + sizeof(int) * N_TOK + sizeof(float) * 2 * N_TOK
                   + sizeof(int) * 2 * NE * N_TOK;
  size_t off_x = (small_end + 255) & ~(size_t)255;
  size_t xbytes = (size_t)N_TOK * DIM * 2;
  size_t off_w = off_x + xbytes;
  size_t wbytes = (size_t)NE * DIM * HID * 2;
  bool full = (ws_size >= off_w + wbytes);

  u16* xb = full ? (u16*)(ws + off_x) : nullptr;

  hipLaunchKernelGGL(gating_kernel, dim3(512), dim3(256), 0, stream,
                     x, Wg, bg, sel, wslot, xb);
  hipLaunchKernelGGL(build_lists_kernel, dim3(16), dim3(256), 0, stream,
                     sel, counts, lists);

  dim3 ggrid(HID / 128, NE * (N_TOK / 128));
  if (full) {
    u16* wt = (u16*)(ws + off_w);
    hipLaunchKernelGGL(transpose_we_kernel, dim3(HID / 64, DIM / 64, NE), dim3(256), 0, stream, We, wt);
    hipLaunchKernelGGL((moe_gemm<0, true>), ggrid, dim3(256), 0, stream,
                       (const void*)xb, (const void*)wt, be, counts, lists, wslot, out);
    hipLaunchKernelGGL((moe_gemm<1, true>), ggrid, dim3(256), 0, stream,
                       (const void*)xb, (const void*)wt, be, counts, lists, wslot, out);
  } else {
    hipLaunchKernelGGL((moe_gemm<0, false>), ggrid, dim3(256), 0, stream,
                       (const void*)x, (const void*)We, be, counts, lists, wslot, out);
    hipLaunchKernelGGL((moe_gemm<1, false>), ggrid, dim3(256), 0, stream,
                       (const void*)x, (const void*)We, be, counts, lists, wslot, out);
  }
}